// Round 4
// baseline (750.866 us; speedup 1.0000x reference)
//
#include <hip/hip_runtime.h>

// FrequencyBandModulation, factored truncated-spectrum form (all bf16 MFMA):
//   W = X*F            (width DFT, 32 complex bins, K=128)      [per image, in LDS]
//   D = Hstk*Wstk      (height DFT on 96 surviving rows, K=256)
//   V_k = Estk_k*Dstk  (masked inverse height, K=192)
//   low_k = Vstk_k*P_k (inverse width c2r, K=64)
//   out = g1*x + (g2-g1)low_1 + (g3-g2)low_2 + (1-g3)low_3
// Matches round-1 verified pocketfft semantics (asymmetric row mask, Im-of-DC drop).

#define NPIX 16384
#define NCHN 256

typedef __attribute__((ext_vector_type(8))) short bf16x8;
typedef __attribute__((ext_vector_type(4))) float f32x4;

__device__ __align__(16) short g_f[64][128];    // W-GEMM B: [n(32R+32I)][q]
__device__ __align__(16) short g_h[192][256];   // D-GEMM A: [dstk(96R+96I)][p-stk] (1/128 folded)
__device__ __align__(16) short g_e[3][256][192];// V-GEMM B: [k][mstk(128R+128I)][dstk]
__device__ __align__(16) short g_p[3][128][64]; // low-GEMM B: [k][nout][jstk] (1/128 folded)

static __device__ __forceinline__ short f2bf(float f) {
  unsigned u = __float_as_uint(f);
  unsigned r = (u + 0x7fffu + ((u >> 16) & 1u)) >> 16;  // RNE
  return (short)r;
}

static __device__ __forceinline__ f32x4 mfma16(bf16x8 a, bf16x8 b, f32x4 c) {
  return __builtin_amdgcn_mfma_f32_16x16x32_bf16(a, b, c, 0, 0, 0);
}

// ---------------- constant tables (every launch; deterministic) ----------------
__global__ __launch_bounds__(256) void const_init_kernel() {
  int idx = blockIdx.x * 256 + threadIdx.x;          // 896 blocks -> 229376
  const float C = 6.2831853071795864769f / 128.f;
  if (idx < 8192) {                                  // g_f[n][q]
    int n = idx >> 7, q = idx & 127;
    int j = n & 31;
    float ang = C * (float)((j * q) & 127);
    float v = (n < 32) ? cosf(ang) : -sinf(ang);
    reinterpret_cast<short*>(g_f)[idx] = f2bf(v);
  } else if (idx < 57344) {                          // g_h[d][kk]
    int e = idx - 8192;
    int d = e >> 8, kk = e & 255;
    int r = (d < 96) ? d : d - 96;
    int ifr = (r < 32) ? r : r + 32;
    float ang = C * (float)((ifr * (kk & 127)) & 127);
    float cv = cosf(ang) * (1.f / 128.f), sv = sinf(ang) * (1.f / 128.f);
    float v = (d < 96) ? ((kk < 128) ? cv : sv) : ((kk < 128) ? -sv : cv);
    reinterpret_cast<short*>(g_h)[e] = f2bf(v);
  } else if (idx < 204800) {                         // g_e[k][mm][kk]
    int e = idx - 57344;
    int k = e / 49152; int e2 = e % 49152;
    int mm = e2 / 192, kk = e2 % 192;
    int nk = 32 >> k;
    int r = (kk < 96) ? kk : kk - 96;
    bool allow = (r < nk) || (r >= 32);
    int ifr = (r < 32) ? r : r + 32;
    float ang = C * (float)((ifr * (mm & 127)) & 127);
    float cv = cosf(ang), sv = sinf(ang);
    float v = (mm < 128) ? ((kk < 96) ? cv : -sv) : ((kk < 96) ? sv : cv);
    reinterpret_cast<short*>(g_e)[e] = f2bf(allow ? v : 0.f);
  } else {                                           // g_p[k][n][jj]
    int e = idx - 204800;
    int k = e / 8192; int e2 = e % 8192;
    int n = e2 >> 6, jj = e2 & 63;
    int nk = 32 >> k;
    int j = jj & 31;
    bool valid = (j < nk) && (jj < 32 || j > 0);
    float wj = (j == 0) ? (1.f / 128.f) : (2.f / 128.f);
    float ang = C * (float)((j * n) & 127);
    float v = (jj < 32) ? (wj * cosf(ang)) : (-wj * sinf(ang));
    reinterpret_cast<short*>(g_p)[e] = f2bf(valid ? v : 0.f);
  }
}

// ---------------- gate coefficient planes into d_ws (unchanged, verified) ----------------
__global__ __launch_bounds__(256) void gates_kernel(
    const float* __restrict__ x, const float* __restrict__ Wg,
    const float* __restrict__ Bg, float* __restrict__ coef) {
  int blk = blockIdx.x;
  int b = blk >> 6;
  int tile = blk & 63;
  int m = ((tile >> 3) << 4) + (threadIdx.x >> 4);
  int n = ((tile & 7) << 4) + (threadIdx.x & 15);
  float a0 = 0.f, a1 = 0.f, a2 = 0.f;
  const float* xb = x + (size_t)b * NCHN * NPIX;
  for (int c = 0; c < NCHN; ++c) {
    const float* xc = xb + (size_t)c * NPIX;
    const float* wc = Wg + c * 9;
    #pragma unroll
    for (int dh = -1; dh <= 1; ++dh) {
      int gm = m + dh;
      bool vm = (unsigned)gm < 128u;
      #pragma unroll
      for (int dw = -1; dw <= 1; ++dw) {
        int gn = n + dw;
        float xv = (vm && (unsigned)gn < 128u) ? xc[gm * 128 + gn] : 0.f;
        int tap = (dh + 1) * 3 + (dw + 1);
        a0 = fmaf(xv, wc[tap], a0);
        a1 = fmaf(xv, wc[2304 + tap], a1);
        a2 = fmaf(xv, wc[4608 + tap], a2);
      }
    }
  }
  a0 += Bg[0]; a1 += Bg[1]; a2 += Bg[2];
  float g1 = 2.f / (1.f + expf(-a0));
  float g2 = 2.f / (1.f + expf(-a1));
  float g3 = 2.f / (1.f + expf(-a2));
  int pix = b * NPIX + m * 128 + n;
  coef[pix]          = g1;
  coef[131072 + pix] = g2 - g1;
  coef[262144 + pix] = g3 - g2;
  coef[393216 + pix] = 1.f - g3;
}

// ---------------- fused spectral kernel: one block per (b,c) image ----------------
__global__ __launch_bounds__(512, 4) void fbm_kernel(
    const float* __restrict__ x, const float* __restrict__ coef,
    float* __restrict__ out) {
  __shared__ __align__(16) short Xs[16384];   // X bf16 [p][q], 256B rows, XOR-swz
  __shared__ __align__(16) short WVs[8192];   // W^T [64n][128p] / V^T [128m][64jstk]
  __shared__ __align__(16) short Ds2[6144];   // D^T [32n][192dstk], 384B rows
  char* XsB = reinterpret_cast<char*>(Xs);
  char* WsB = reinterpret_cast<char*>(WVs);
  char* DsB = reinterpret_cast<char*>(Ds2);

  int t = threadIdx.x;
  int img = blockIdx.x;
  int b = img >> 8;
  const float* xg = x + (size_t)img * NPIX;
  int lane = t & 63, w = t >> 6;
  int l15 = lane & 15, l4 = lane >> 4;
  const f32x4 zero = {0.f, 0.f, 0.f, 0.f};

  {  // load X -> bf16 swizzled LDS
    int row = t >> 2, c0 = (t & 3) * 32;
    const float4* src = reinterpret_cast<const float4*>(xg + row * 128 + c0);
    int sw = (row & 7) << 4;
    #pragma unroll
    for (int i = 0; i < 8; ++i) {
      float4 v = src[i];
      short4 s;
      s.x = f2bf(v.x); s.y = f2bf(v.y); s.z = f2bf(v.z); s.w = f2bf(v.w);
      int byte = row * 256 + (((c0 + i * 4) * 2) ^ sw);
      *reinterpret_cast<short4*>(XsB + byte) = s;
    }
  }

  // output accumulator tile mapping (fixed across phases): wave covers
  // Mtiles {Mg*4+mt}, Ntiles {Ng*2+nt};  pix = (Mtile*16+l4*4+r)*128 + Ntile*16+l15
  int Mg3 = w >> 2, Ng3 = w & 3;
  f32x4 oacc[4][2];
  {  // init: g1 * x  (exact f32, L1/L2-hot re-read)
    const float* c0p = coef + (size_t)b * NPIX;
    #pragma unroll
    for (int mt = 0; mt < 4; ++mt) {
      int m0 = (Mg3 * 4 + mt) * 16 + l4 * 4;
      #pragma unroll
      for (int nt = 0; nt < 2; ++nt) {
        int nout = (Ng3 * 2 + nt) * 16 + l15;
        #pragma unroll
        for (int r = 0; r < 4; ++r) {
          int pix = (m0 + r) * 128 + nout;
          oacc[mt][nt][r] = c0p[pix] * xg[pix];
        }
      }
    }
  }
  __syncthreads();

  // ---- P0: W = X*F  (M=p 8 tiles, N=64 4 tiles; wave: Ntile=w&3, Mquad=w>>2) ----
  {
    int Ntile = w & 3, Mq = w >> 2;
    int n = Ntile * 16 + l15;
    f32x4 acc[4] = {zero, zero, zero, zero};
    #pragma unroll
    for (int ks = 0; ks < 4; ++ks) {
      int koff = ks * 32 + l4 * 8;
      bf16x8 bf = *reinterpret_cast<const bf16x8*>(&g_f[n][koff]);
      #pragma unroll
      for (int mt = 0; mt < 4; ++mt) {
        int p = (Mq * 4 + mt) * 16 + l15;
        bf16x8 a = *reinterpret_cast<const bf16x8*>(
            XsB + p * 256 + ((koff * 2) ^ ((p & 7) << 4)));
        acc[mt] = mfma16(a, bf, acc[mt]);
      }
    }
    #pragma unroll
    for (int mt = 0; mt < 4; ++mt) {
      int p0 = (Mq * 4 + mt) * 16 + l4 * 4;
      short4 s;
      s.x = f2bf(acc[mt][0]); s.y = f2bf(acc[mt][1]);
      s.z = f2bf(acc[mt][2]); s.w = f2bf(acc[mt][3]);
      *reinterpret_cast<short4*>(WsB + n * 256 + ((p0 * 2) ^ ((n & 7) << 4))) = s;
    }
  }
  __syncthreads();

  // ---- P1: D = Hstk*Wstk  (M=dstk 12 tiles, N=n 2 tiles; wave: Nt=w&1, Mt3=w>>1) ----
  {
    int Ntile = w & 1, Mt3 = w >> 1;
    int n = Ntile * 16 + l15;
    f32x4 acc[3] = {zero, zero, zero};
    #pragma unroll
    for (int ks = 0; ks < 8; ++ks) {
      int koff = ks * 32 + l4 * 8;
      int wrow = n + ((ks >= 4) ? 32 : 0);
      bf16x8 bb = *reinterpret_cast<const bf16x8*>(
          WsB + wrow * 256 + ((((koff & 127)) * 2) ^ ((wrow & 7) << 4)));
      #pragma unroll
      for (int mt = 0; mt < 3; ++mt) {
        int d = (Mt3 * 3 + mt) * 16 + l15;
        bf16x8 aa = *reinterpret_cast<const bf16x8*>(&g_h[d][koff]);
        acc[mt] = mfma16(aa, bb, acc[mt]);
      }
    }
    #pragma unroll
    for (int mt = 0; mt < 3; ++mt) {
      int d0 = (Mt3 * 3 + mt) * 16 + l4 * 4;
      short4 s;
      s.x = f2bf(acc[mt][0]); s.y = f2bf(acc[mt][1]);
      s.z = f2bf(acc[mt][2]); s.w = f2bf(acc[mt][3]);
      *reinterpret_cast<short4*>(DsB + n * 384 + ((d0 * 2) ^ ((n & 7) << 4))) = s;
    }
  }
  __syncthreads();

  for (int k = 0; k < 3; ++k) {
    // ---- P2: V_k = Estk_k*Dstk  (M=mstk 16 tiles, N=j 2 tiles; wave: Mtiles {2w,2w+1}, both Ntiles) ----
    {
      f32x4 acc[2][2] = {{zero, zero}, {zero, zero}};
      #pragma unroll
      for (int ks = 0; ks < 6; ++ks) {
        int koff = ks * 32 + l4 * 8;
        bf16x8 b0 = *reinterpret_cast<const bf16x8*>(
            DsB + l15 * 384 + ((koff * 2) ^ ((l15 & 7) << 4)));
        int j1 = 16 + l15;
        bf16x8 b1 = *reinterpret_cast<const bf16x8*>(
            DsB + j1 * 384 + ((koff * 2) ^ ((j1 & 7) << 4)));
        #pragma unroll
        for (int mi = 0; mi < 2; ++mi) {
          int mstk = (2 * w + mi) * 16 + l15;
          bf16x8 aa = *reinterpret_cast<const bf16x8*>(&g_e[k][mstk][koff]);
          acc[mi][0] = mfma16(aa, b0, acc[mi][0]);
          acc[mi][1] = mfma16(aa, b1, acc[mi][1]);
        }
      }
      #pragma unroll
      for (int mi = 0; mi < 2; ++mi) {
        #pragma unroll
        for (int ni = 0; ni < 2; ++ni) {
          int j = ni * 16 + l15;
          #pragma unroll
          for (int r = 0; r < 4; ++r) {
            int mstk = (2 * w + mi) * 16 + l4 * 4 + r;
            int m = mstk & 127;
            int jst = ((mstk >> 7) << 5) + j;
            *reinterpret_cast<short*>(WsB + m * 128 + ((jst * 2) ^ ((m & 7) << 4))) =
                f2bf(acc[mi][ni][r]);
          }
        }
      }
    }
    __syncthreads();
    // ---- P3: low_k = Vstk*P_k + fold  (M=m 8 tiles, N=nout 8 tiles; wave: Mg3/Ng3) ----
    {
      f32x4 acc[4][2] = {{zero, zero}, {zero, zero}, {zero, zero}, {zero, zero}};
      #pragma unroll
      for (int ks = 0; ks < 2; ++ks) {
        int koff = ks * 32 + l4 * 8;
        bf16x8 bfr[2];
        #pragma unroll
        for (int nt = 0; nt < 2; ++nt) {
          int nout = (Ng3 * 2 + nt) * 16 + l15;
          bfr[nt] = *reinterpret_cast<const bf16x8*>(&g_p[k][nout][koff]);
        }
        #pragma unroll
        for (int mt = 0; mt < 4; ++mt) {
          int m = (Mg3 * 4 + mt) * 16 + l15;
          bf16x8 aa = *reinterpret_cast<const bf16x8*>(
              WsB + m * 128 + ((koff * 2) ^ ((m & 7) << 4)));
          acc[mt][0] = mfma16(aa, bfr[0], acc[mt][0]);
          acc[mt][1] = mfma16(aa, bfr[1], acc[mt][1]);
        }
      }
      const float* cfp = coef + (size_t)(k + 1) * 131072 + (size_t)b * NPIX;
      #pragma unroll
      for (int mt = 0; mt < 4; ++mt) {
        int m0 = (Mg3 * 4 + mt) * 16 + l4 * 4;
        #pragma unroll
        for (int nt = 0; nt < 2; ++nt) {
          int nout = (Ng3 * 2 + nt) * 16 + l15;
          #pragma unroll
          for (int r = 0; r < 4; ++r)
            oacc[mt][nt][r] = fmaf(cfp[(m0 + r) * 128 + nout], acc[mt][nt][r],
                                   oacc[mt][nt][r]);
        }
      }
    }
    if (k < 2) __syncthreads();
  }

  float* og = out + (size_t)img * NPIX;
  #pragma unroll
  for (int mt = 0; mt < 4; ++mt) {
    int m0 = (Mg3 * 4 + mt) * 16 + l4 * 4;
    #pragma unroll
    for (int nt = 0; nt < 2; ++nt) {
      int nout = (Ng3 * 2 + nt) * 16 + l15;
      #pragma unroll
      for (int r = 0; r < 4; ++r)
        og[(m0 + r) * 128 + nout] = oacc[mt][nt][r];
    }
  }
}

extern "C" void kernel_launch(void* const* d_in, const int* in_sizes, int n_in,
                              void* d_out, int out_size, void* d_ws, size_t ws_size,
                              hipStream_t stream) {
  const float* x  = (const float*)d_in[0];
  const float* Wg = (const float*)d_in[1];
  const float* Bg = (const float*)d_in[2];
  float* out  = (float*)d_out;
  float* coef = (float*)d_ws;   // 4 planes * 8 * 16384 * 4B = 2 MiB
  const_init_kernel<<<896, 256, 0, stream>>>();
  gates_kernel<<<512, 256, 0, stream>>>(x, Wg, Bg, coef);
  fbm_kernel<<<2048, 512, 0, stream>>>(x, coef, out);
}

// Round 5
// 499.442 us; speedup vs baseline: 1.5034x; 1.5034x over previous
//
#include <hip/hip_runtime.h>

// FrequencyBandModulation, factored truncated-spectrum form (all bf16 MFMA):
//   W = X*F            (width DFT, 32 complex bins, K=128)      [per image, in LDS]
//   D = Hstk*Wstk      (height DFT on 96 surviving rows, K=256)
//   V_k = Estk_k*Dstk  (masked inverse height, K=192)
//   low_k = Vstk_k*P_k (inverse width c2r, K=64) -> bf16 LDS plane
//   out = g1*x + (g2-g1)low_1 + (g3-g2)low_2 + (1-g3)low_3   (coalesced f32 epilogue)
// Matches round-1 verified pocketfft semantics (asymmetric row mask, Im-of-DC drop).

#define NPIX 16384
#define NCHN 256

typedef __attribute__((ext_vector_type(8))) short bf16x8;
typedef __attribute__((ext_vector_type(4))) float f32x4;

__device__ __align__(16) short g_f[64][128];    // W-GEMM B: [n(32R+32I)][q]
__device__ __align__(16) short g_h[192][256];   // D-GEMM A: [dstk(96R+96I)][p-stk] (1/128 folded)
__device__ __align__(16) short g_e[3][256][192];// V-GEMM B: [k][mstk(128R+128I)][dstk]
__device__ __align__(16) short g_p[3][128][64]; // low-GEMM B: [k][nout][jstk] (1/128 folded)

static __device__ __forceinline__ short f2bf(float f) {
  unsigned u = __float_as_uint(f);
  unsigned r = (u + 0x7fffu + ((u >> 16) & 1u)) >> 16;  // RNE
  return (short)r;
}
static __device__ __forceinline__ float bf2f(short s) {
  return __uint_as_float(((unsigned)(unsigned short)s) << 16);
}

static __device__ __forceinline__ f32x4 mfma16(bf16x8 a, bf16x8 b, f32x4 c) {
  return __builtin_amdgcn_mfma_f32_16x16x32_bf16(a, b, c, 0, 0, 0);
}

// ---------------- constant tables (every launch; deterministic) ----------------
__global__ __launch_bounds__(256) void const_init_kernel() {
  int idx = blockIdx.x * 256 + threadIdx.x;          // 896 blocks -> 229376
  const float C = 6.2831853071795864769f / 128.f;
  if (idx < 8192) {                                  // g_f[n][q]
    int n = idx >> 7, q = idx & 127;
    int j = n & 31;
    float ang = C * (float)((j * q) & 127);
    float v = (n < 32) ? cosf(ang) : -sinf(ang);
    reinterpret_cast<short*>(g_f)[idx] = f2bf(v);
  } else if (idx < 57344) {                          // g_h[d][kk]
    int e = idx - 8192;
    int d = e >> 8, kk = e & 255;
    int r = (d < 96) ? d : d - 96;
    int ifr = (r < 32) ? r : r + 32;
    float ang = C * (float)((ifr * (kk & 127)) & 127);
    float cv = cosf(ang) * (1.f / 128.f), sv = sinf(ang) * (1.f / 128.f);
    float v = (d < 96) ? ((kk < 128) ? cv : sv) : ((kk < 128) ? -sv : cv);
    reinterpret_cast<short*>(g_h)[e] = f2bf(v);
  } else if (idx < 204800) {                         // g_e[k][mm][kk]
    int e = idx - 57344;
    int k = e / 49152; int e2 = e % 49152;
    int mm = e2 / 192, kk = e2 % 192;
    int nk = 32 >> k;
    int r = (kk < 96) ? kk : kk - 96;
    bool allow = (r < nk) || (r >= 32);
    int ifr = (r < 32) ? r : r + 32;
    float ang = C * (float)((ifr * (mm & 127)) & 127);
    float cv = cosf(ang), sv = sinf(ang);
    float v = (mm < 128) ? ((kk < 96) ? cv : -sv) : ((kk < 96) ? sv : cv);
    reinterpret_cast<short*>(g_e)[e] = f2bf(allow ? v : 0.f);
  } else {                                           // g_p[k][n][jj]
    int e = idx - 204800;
    int k = e / 8192; int e2 = e % 8192;
    int n = e2 >> 6, jj = e2 & 63;
    int nk = 32 >> k;
    int j = jj & 31;
    bool valid = (j < nk) && (jj < 32 || j > 0);
    float wj = (j == 0) ? (1.f / 128.f) : (2.f / 128.f);
    float ang = C * (float)((j * n) & 127);
    float v = (jj < 32) ? (wj * cosf(ang)) : (-wj * sinf(ang));
    reinterpret_cast<short*>(g_p)[e] = f2bf(valid ? v : 0.f);
  }
}

// ---------------- gate coefficient planes into d_ws (unchanged, verified) ----------------
__global__ __launch_bounds__(256) void gates_kernel(
    const float* __restrict__ x, const float* __restrict__ Wg,
    const float* __restrict__ Bg, float* __restrict__ coef) {
  int blk = blockIdx.x;
  int b = blk >> 6;
  int tile = blk & 63;
  int m = ((tile >> 3) << 4) + (threadIdx.x >> 4);
  int n = ((tile & 7) << 4) + (threadIdx.x & 15);
  float a0 = 0.f, a1 = 0.f, a2 = 0.f;
  const float* xb = x + (size_t)b * NCHN * NPIX;
  for (int c = 0; c < NCHN; ++c) {
    const float* xc = xb + (size_t)c * NPIX;
    const float* wc = Wg + c * 9;
    #pragma unroll
    for (int dh = -1; dh <= 1; ++dh) {
      int gm = m + dh;
      bool vm = (unsigned)gm < 128u;
      #pragma unroll
      for (int dw = -1; dw <= 1; ++dw) {
        int gn = n + dw;
        float xv = (vm && (unsigned)gn < 128u) ? xc[gm * 128 + gn] : 0.f;
        int tap = (dh + 1) * 3 + (dw + 1);
        a0 = fmaf(xv, wc[tap], a0);
        a1 = fmaf(xv, wc[2304 + tap], a1);
        a2 = fmaf(xv, wc[4608 + tap], a2);
      }
    }
  }
  a0 += Bg[0]; a1 += Bg[1]; a2 += Bg[2];
  float g1 = 2.f / (1.f + expf(-a0));
  float g2 = 2.f / (1.f + expf(-a1));
  float g3 = 2.f / (1.f + expf(-a2));
  int pix = b * NPIX + m * 128 + n;
  coef[pix]          = g1;
  coef[131072 + pix] = g2 - g1;
  coef[262144 + pix] = g3 - g2;
  coef[393216 + pix] = 1.f - g3;
}

// ---------------- fused spectral kernel: one block per (b,c) image ----------------
__global__ __launch_bounds__(512, 4) void fbm_kernel(
    const float* __restrict__ x, const float* __restrict__ coef,
    float* __restrict__ out) {
  // PlaneXs: X bf16 [p][q] (staging, swz (row&7)<<4 on bytes) ALIASED with
  //          low bf16 plane [row][col] (swz (row&7)<<2 on elements)
  __shared__ __align__(16) short PlaneXs[16384];  // 32 KB
  __shared__ __align__(16) short WVs[8192];       // 16 KB: W^T / V^T
  __shared__ __align__(16) short Ds2[6144];       // 12 KB: D^T [32n][192dstk]
  char* XsB = reinterpret_cast<char*>(PlaneXs);
  char* PlaneB = XsB;
  char* WsB = reinterpret_cast<char*>(WVs);
  char* DsB = reinterpret_cast<char*>(Ds2);

  int t = threadIdx.x;
  int img = blockIdx.x;
  int b = img >> 8;
  const float* xg = x + (size_t)img * NPIX;
  int lane = t & 63, w = t >> 6;
  int l15 = lane & 15, l4 = lane >> 4;
  const f32x4 zero = {0.f, 0.f, 0.f, 0.f};

  // ---- coalesced load: x + coef0 -> oaccC (f32 regs) and bf16 Xs staging ----
  float4 oaccC[8];
  {
    const float4* xv4 = reinterpret_cast<const float4*>(xg);
    const float4* cf0 = reinterpret_cast<const float4*>(coef + (size_t)b * NPIX);
    #pragma unroll
    for (int i = 0; i < 8; ++i) {
      int f = t + i * 512;              // float4 id; pixel = f*4
      float4 xv = xv4[f];
      float4 c0 = cf0[f];
      oaccC[i].x = xv.x * c0.x;
      oaccC[i].y = xv.y * c0.y;
      oaccC[i].z = xv.z * c0.z;
      oaccC[i].w = xv.w * c0.w;
      int row = f >> 5;
      int byte = row * 256 + (((f & 31) * 8) ^ ((row & 7) << 4));
      short4 s;
      s.x = f2bf(xv.x); s.y = f2bf(xv.y); s.z = f2bf(xv.z); s.w = f2bf(xv.w);
      *reinterpret_cast<short4*>(XsB + byte) = s;
    }
  }
  __syncthreads();

  // ---- P0: W = X*F  (M=p 8 tiles, N=64 4 tiles) ----
  {
    int Ntile = w & 3, Mq = w >> 2;
    int n = Ntile * 16 + l15;
    f32x4 acc[4] = {zero, zero, zero, zero};
    #pragma unroll
    for (int ks = 0; ks < 4; ++ks) {
      int koff = ks * 32 + l4 * 8;
      bf16x8 bf = *reinterpret_cast<const bf16x8*>(&g_f[n][koff]);
      #pragma unroll
      for (int mt = 0; mt < 4; ++mt) {
        int p = (Mq * 4 + mt) * 16 + l15;
        bf16x8 a = *reinterpret_cast<const bf16x8*>(
            XsB + p * 256 + ((koff * 2) ^ ((p & 7) << 4)));
        acc[mt] = mfma16(a, bf, acc[mt]);
      }
    }
    #pragma unroll
    for (int mt = 0; mt < 4; ++mt) {
      int p0 = (Mq * 4 + mt) * 16 + l4 * 4;
      short4 s;
      s.x = f2bf(acc[mt][0]); s.y = f2bf(acc[mt][1]);
      s.z = f2bf(acc[mt][2]); s.w = f2bf(acc[mt][3]);
      *reinterpret_cast<short4*>(WsB + n * 256 + ((p0 * 2) ^ ((n & 7) << 4))) = s;
    }
  }
  __syncthreads();

  // ---- P1: D = Hstk*Wstk  (M=dstk 12 tiles, N=n 2 tiles) ----
  {
    int Ntile = w & 1, Mt3 = w >> 1;
    int n = Ntile * 16 + l15;
    f32x4 acc[3] = {zero, zero, zero};
    #pragma unroll
    for (int ks = 0; ks < 8; ++ks) {
      int koff = ks * 32 + l4 * 8;
      int wrow = n + ((ks >= 4) ? 32 : 0);
      bf16x8 bb = *reinterpret_cast<const bf16x8*>(
          WsB + wrow * 256 + (((koff & 127) * 2) ^ ((wrow & 7) << 4)));
      #pragma unroll
      for (int mt = 0; mt < 3; ++mt) {
        int d = (Mt3 * 3 + mt) * 16 + l15;
        bf16x8 aa = *reinterpret_cast<const bf16x8*>(&g_h[d][koff]);
        acc[mt] = mfma16(aa, bb, acc[mt]);
      }
    }
    #pragma unroll
    for (int mt = 0; mt < 3; ++mt) {
      int d0 = (Mt3 * 3 + mt) * 16 + l4 * 4;
      short4 s;
      s.x = f2bf(acc[mt][0]); s.y = f2bf(acc[mt][1]);
      s.z = f2bf(acc[mt][2]); s.w = f2bf(acc[mt][3]);
      *reinterpret_cast<short4*>(DsB + n * 384 + ((d0 * 2) ^ ((n & 7) << 4))) = s;
    }
  }
  __syncthreads();

  int Mg3 = w >> 2, Ng3 = w & 3;
  for (int k = 0; k < 3; ++k) {
    // ---- P2: V_k = Estk_k*Dstk (M=mstk 16 tiles, N=j 2 tiles) ----
    {
      f32x4 acc[2][2] = {{zero, zero}, {zero, zero}};
      #pragma unroll
      for (int ks = 0; ks < 6; ++ks) {
        int koff = ks * 32 + l4 * 8;
        bf16x8 b0 = *reinterpret_cast<const bf16x8*>(
            DsB + l15 * 384 + ((koff * 2) ^ ((l15 & 7) << 4)));
        int j1 = 16 + l15;
        bf16x8 b1 = *reinterpret_cast<const bf16x8*>(
            DsB + j1 * 384 + ((koff * 2) ^ ((j1 & 7) << 4)));
        #pragma unroll
        for (int mi = 0; mi < 2; ++mi) {
          int mstk = (2 * w + mi) * 16 + l15;
          bf16x8 aa = *reinterpret_cast<const bf16x8*>(&g_e[k][mstk][koff]);
          acc[mi][0] = mfma16(aa, b0, acc[mi][0]);
          acc[mi][1] = mfma16(aa, b1, acc[mi][1]);
        }
      }
      #pragma unroll
      for (int mi = 0; mi < 2; ++mi) {
        #pragma unroll
        for (int ni = 0; ni < 2; ++ni) {
          int j = ni * 16 + l15;
          #pragma unroll
          for (int r = 0; r < 4; ++r) {
            int mstk = (2 * w + mi) * 16 + l4 * 4 + r;
            int m = mstk & 127;
            int jst = ((mstk >> 7) << 5) + j;
            *reinterpret_cast<short*>(WsB + m * 128 + ((jst * 2) ^ ((m & 7) << 4))) =
                f2bf(acc[mi][ni][r]);
          }
        }
      }
    }
    __syncthreads();
    // ---- P3: low_k = Vstk*P_k -> bf16 Plane (swizzled scatter) ----
    {
      f32x4 acc[4][2] = {{zero, zero}, {zero, zero}, {zero, zero}, {zero, zero}};
      #pragma unroll
      for (int ks = 0; ks < 2; ++ks) {
        int koff = ks * 32 + l4 * 8;
        bf16x8 bfr[2];
        #pragma unroll
        for (int nt = 0; nt < 2; ++nt) {
          int nout = (Ng3 * 2 + nt) * 16 + l15;
          bfr[nt] = *reinterpret_cast<const bf16x8*>(&g_p[k][nout][koff]);
        }
        #pragma unroll
        for (int mt = 0; mt < 4; ++mt) {
          int m = (Mg3 * 4 + mt) * 16 + l15;
          bf16x8 aa = *reinterpret_cast<const bf16x8*>(
              WsB + m * 128 + ((koff * 2) ^ ((m & 7) << 4)));
          acc[mt][0] = mfma16(aa, bfr[0], acc[mt][0]);
          acc[mt][1] = mfma16(aa, bfr[1], acc[mt][1]);
        }
      }
      #pragma unroll
      for (int mt = 0; mt < 4; ++mt) {
        #pragma unroll
        for (int nt = 0; nt < 2; ++nt) {
          int col = (Ng3 * 2 + nt) * 16 + l15;
          #pragma unroll
          for (int r = 0; r < 4; ++r) {
            int row = (Mg3 * 4 + mt) * 16 + l4 * 4 + r;
            int byte = row * 256 + ((col ^ ((row & 7) << 2)) << 1);
            *reinterpret_cast<short*>(PlaneB + byte) = f2bf(acc[mt][nt][r]);
          }
        }
      }
    }
    __syncthreads();
    // ---- fold: coalesced coef read + LDS plane read ----
    {
      const float4* cfk = reinterpret_cast<const float4*>(
          coef + (size_t)(k + 1) * 131072 + (size_t)b * NPIX);
      #pragma unroll
      for (int i = 0; i < 8; ++i) {
        int f = t + i * 512;
        int row = f >> 5;
        int col = (f & 31) * 4;
        int byte = row * 256 + ((col ^ ((row & 7) << 2)) << 1);
        short4 s = *reinterpret_cast<const short4*>(PlaneB + byte);
        float4 cv = cfk[f];
        oaccC[i].x = fmaf(cv.x, bf2f(s.x), oaccC[i].x);
        oaccC[i].y = fmaf(cv.y, bf2f(s.y), oaccC[i].y);
        oaccC[i].z = fmaf(cv.z, bf2f(s.z), oaccC[i].z);
        oaccC[i].w = fmaf(cv.w, bf2f(s.w), oaccC[i].w);
      }
    }
    if (k < 2) __syncthreads();
  }

  // ---- coalesced float4 store ----
  float4* og4 = reinterpret_cast<float4*>(out + (size_t)img * NPIX);
  #pragma unroll
  for (int i = 0; i < 8; ++i) og4[t + i * 512] = oaccC[i];
}

extern "C" void kernel_launch(void* const* d_in, const int* in_sizes, int n_in,
                              void* d_out, int out_size, void* d_ws, size_t ws_size,
                              hipStream_t stream) {
  const float* x  = (const float*)d_in[0];
  const float* Wg = (const float*)d_in[1];
  const float* Bg = (const float*)d_in[2];
  float* out  = (float*)d_out;
  float* coef = (float*)d_ws;   // 4 planes * 8 * 16384 * 4B = 2 MiB
  const_init_kernel<<<896, 256, 0, stream>>>();
  gates_kernel<<<512, 256, 0, stream>>>(x, Wg, Bg, coef);
  fbm_kernel<<<2048, 512, 0, stream>>>(x, coef, out);
}